// Round 1
// baseline (195.687 us; speedup 1.0000x reference)
//
#include <hip/hip_runtime.h>

// crossCorrelation3D: local (9x9x9) normalized cross-correlation loss, fused.
// B=2, C=1, D=H=W=160, fp32. Output = -mean(cc), scalar.
//
// R1 changes vs baseline (97.7us main kernel, latency-bound: MfmaUtil 0,
// VALUBusy 41%, HBM 27%, Occupancy 39%, bank-conflict cycles ~19%):
//  1. DCHUNK 32->16: grid 1000->2000 blocks (~7.8 blocks/CU vs 3.9) for TLP.
//  2. T14 pipeline: issue next plane's halo global loads into registers
//     BEFORE the current plane's barriers/compute; LDS staging writes the
//     regs loaded last iteration. Flow value prefetched at iteration top.
//  3. LDS pad: tmp5 field stride 384->392, Pbuf 256->264 (mod 32 = 8) so
//     the 4 f-values per wave spread across banks (4-way -> 2-way = free).
//
// NOTE: reference transforms target t=(raw+1)/2 BEFORE zero-padded box sum,
// so padding must contribute t=0 (not 0.5). Transform applied at load time
// for in-bounds voxels only; out-of-range D planes contribute all-zero
// planes (computed on zero-filled regs, yielding Pbuf == 0).

constexpr int NB = 2;
constexpr int ND = 160;
constexpr int NH = 160;
constexpr int NW = 160;
constexpr int TH = 16;
constexpr int TW = 16;
constexpr int DCHUNK = 16;
constexpr int NDCH = ND / DCHUNK;            // 10
constexpr int NPL = DCHUNK + 8;              // 24 planes marched per block
constexpr int FS5 = 392;                     // tmp5 field stride (24*16 + 8 pad)
constexpr int PFS = 264;                     // Pbuf field stride (256 + 8 pad)
constexpr float INV_K = 1.0f / 729.0f;
constexpr double INV_COUNT = 1.0 / (double(NB) * ND * NH * NW); // 1/8192000

// Issue global loads of one 24x24 halo plane (input & target) into registers.
// tid<144: each thread owns one float4 of the 24x(6*float4) plane.
// w0-4 is a multiple of 4 so rows are float4-aligned; each 4-wide segment is
// entirely in-bounds or entirely out (w0 % 16 == 0, halo = 4).
__device__ __forceinline__ void issue_load(
    const float* __restrict__ in, const float* __restrict__ tg,
    int b, int dp, int h0, int w0, int tid,
    float4& iv, float4& tv)
{
    iv = make_float4(0.f, 0.f, 0.f, 0.f);
    tv = make_float4(0.f, 0.f, 0.f, 0.f);
    if (tid < 144 && ((unsigned)dp < (unsigned)ND)) {
        int r = tid / 6;
        int q = tid - r * 6;
        int gh = h0 - 4 + r;
        int gw = w0 - 4 + q * 4;
        if (((unsigned)gh < (unsigned)NH) && ((unsigned)gw < (unsigned)NW)) {
            int base = ((b * ND + dp) * NH + gh) * NW + gw;   // fits int32
            iv = *reinterpret_cast<const float4*>(in + base);
            float4 rv = *reinterpret_cast<const float4*>(tg + base);
            tv.x = fmaf(rv.x, 0.5f, 0.5f);
            tv.y = fmaf(rv.y, 0.5f, 0.5f);
            tv.z = fmaf(rv.z, 0.5f, 0.5f);
            tv.w = fmaf(rv.w, 0.5f, 0.5f);
        }
    }
}

__device__ __forceinline__ void stage(int tid, const float4& iv, const float4& tv,
                                      float* __restrict__ inT, float* __restrict__ tgT)
{
    if (tid < 144) {
        reinterpret_cast<float4*>(inT)[tid] = iv;   // row stride 24 floats = 6 float4
        reinterpret_cast<float4*>(tgT)[tid] = tv;
    }
}

// w-direction 9-sums of 5 product fields -> tmp5[5][24][16] (field stride FS5)
__device__ __forceinline__ void step2(int tid, const float* __restrict__ inT,
                                      const float* __restrict__ tgT,
                                      float* __restrict__ tmp5)
{
    int pos = tid;
    #pragma unroll
    for (int rep = 0; rep < 2; ++rep) {
        if (pos < 384) {
            int r = pos >> 4, wo = pos & 15;
            const float* ir = inT + r * 24 + wo;
            const float* tr = tgT + r * 24 + wo;
            float s0 = 0.f, s1 = 0.f, s2 = 0.f, s3 = 0.f, s4 = 0.f;
            #pragma unroll
            for (int k = 0; k < 9; ++k) {
                float ivv = ir[k];
                float t = tr[k];            // already transformed (pad=0)
                s0 += t;
                s1 += ivv;
                s2 = fmaf(t, t, s2);
                s3 = fmaf(ivv, ivv, s3);
                s4 = fmaf(ivv, t, s4);
            }
            int o = r * 16 + wo;
            tmp5[0 * FS5 + o] = s0;
            tmp5[1 * FS5 + o] = s1;
            tmp5[2 * FS5 + o] = s2;
            tmp5[3 * FS5 + o] = s3;
            tmp5[4 * FS5 + o] = s4;
        }
        pos += 256;
    }
}

// h-direction sliding 9-sums -> Pbuf[5][16][16] (field stride PFS)
__device__ __forceinline__ void step3(int tid, const float* __restrict__ tmp5,
                                      float* __restrict__ Pbuf)
{
    if (tid < 80) {
        int f = tid >> 4, w = tid & 15;
        const float* basep = tmp5 + f * FS5 + w;
        float s = 0.f;
        #pragma unroll
        for (int r = 0; r < 8; ++r) s += basep[r * 16];
        #pragma unroll
        for (int ho = 0; ho < 16; ++ho) {
            s += basep[(ho + 8) * 16];
            Pbuf[f * PFS + ho * 16 + w] = s;
            s -= basep[ho * 16];
        }
    }
}

__device__ __forceinline__ float cc_value(const float S[5], float flv)
{
    float wgt = 1.0f / (1.0f + __expf(-flv));   // sigmoid, GAMMA=1
    float Ts = S[0], Is = S[1], TTs = S[2], IIs = S[3], ITs = S[4];
    float Ihat = Is * INV_K;
    float That = Ts * INV_K;
    float cross = ITs - Ihat * Ts - That * Is + That * Ihat * 729.0f;
    float T_var = TTs - 2.0f * That * Ts + That * That * 729.0f;
    float I_var = IIs - 2.0f * Ihat * Is + Ihat * Ihat * 729.0f;
    return cross * cross * wgt / (T_var * I_var + 1e-5f);
}

__global__ void __launch_bounds__(256)
cc3d_main(const float* __restrict__ in, const float* __restrict__ tg,
          const float* __restrict__ fl, double* __restrict__ acc_out)
{
    __shared__ float inT[24 * 24];
    __shared__ float tgT[24 * 24];
    __shared__ float tmp5[5 * FS5];
    __shared__ float Pbuf[5 * PFS];
    __shared__ float red[4];

    const int tid = threadIdx.x;
    const int w0 = blockIdx.x * TW;
    const int h0 = blockIdx.y * TH;
    const int bz = blockIdx.z;
    const int b  = bz / NDCH;
    const int d0 = (bz - b * NDCH) * DCHUNK;
    const int hh = tid >> 4, ww = tid & 15;

    // D-direction ring of 9 plane values per field, statically indexed.
    float ring[45];
    #pragma unroll
    for (int i = 0; i < 45; ++i) ring[i] = 0.f;
    float S[5] = {0.f, 0.f, 0.f, 0.f, 0.f};
    float acc = 0.f;

    // Pipeline prologue: loads for plane 0 (dp = d0-4) in flight.
    float4 iv, tv;
    issue_load(in, tg, b, d0 - 4, h0, w0, tid, iv, tv);

    // ---- planes l = 0..8: prefill slots 0..7 + first output (l=8, j=0) ----
    #pragma unroll
    for (int l = 0; l < 9; ++l) {
        stage(tid, iv, tv, inT, tgT);
        float4 niv, ntv;
        issue_load(in, tg, b, d0 - 4 + l + 1, h0, w0, tid, niv, ntv);
        float flv = 0.f;
        if (l == 8) {
            int fidx = ((b * ND + d0) * NH + (h0 + hh)) * NW + (w0 + ww);
            flv = fl[fidx];
        }
        __syncthreads();
        step2(tid, inT, tgT, tmp5);
        __syncthreads();
        step3(tid, tmp5, Pbuf);
        __syncthreads();
        if (l < 8) {
            #pragma unroll
            for (int f = 0; f < 5; ++f) {
                float pv = Pbuf[f * PFS + tid];
                ring[f * 9 + l] = pv;
                S[f] += pv;
            }
        } else {
            #pragma unroll
            for (int f = 0; f < 5; ++f) {
                float pn = Pbuf[f * PFS + tid];
                S[f] += pn - ring[f * 9 + 8];
                ring[f * 9 + 8] = pn;
            }
            acc += cc_value(S, flv);
        }
        iv = niv; tv = ntv;
    }

    // ---- planes l = 9..NPL-1: outputs j = 1..DCHUNK-1 ----
    // l = lb + li with lb multiple of 9 => ring slot = li (compile-time).
    for (int lb = 9; lb < 27; lb += 9) {
        #pragma unroll
        for (int li = 0; li < 9; ++li) {
            const int l = lb + li;
            if (l < NPL) {                    // block-uniform guard
                stage(tid, iv, tv, inT, tgT);
                float4 niv, ntv;
                if (l < NPL - 1) {
                    issue_load(in, tg, b, d0 - 4 + l + 1, h0, w0, tid, niv, ntv);
                } else {
                    niv = make_float4(0.f, 0.f, 0.f, 0.f);
                    ntv = niv;
                }
                int dout = d0 + (l - 8);
                int fidx = ((b * ND + dout) * NH + (h0 + hh)) * NW + (w0 + ww);
                float flv = fl[fidx];
                __syncthreads();
                step2(tid, inT, tgT, tmp5);
                __syncthreads();
                step3(tid, tmp5, Pbuf);
                __syncthreads();
                const int slot = li;
                #pragma unroll
                for (int f = 0; f < 5; ++f) {
                    float pn = Pbuf[f * PFS + tid];
                    S[f] += pn - ring[f * 9 + slot];
                    ring[f * 9 + slot] = pn;
                }
                acc += cc_value(S, flv);
                iv = niv; tv = ntv;
            }
        }
    }

    // ---- block reduction -> double atomic into workspace ----
    #pragma unroll
    for (int off = 32; off > 0; off >>= 1) acc += __shfl_down(acc, off);
    if ((tid & 63) == 0) red[tid >> 6] = acc;
    __syncthreads();
    if (tid == 0) {
        double v = (double)red[0] + (double)red[1] + (double)red[2] + (double)red[3];
        atomicAdd(acc_out, v);
    }
}

__global__ void cc3d_finalize(const double* __restrict__ acc, float* __restrict__ out)
{
    out[0] = (float)(-(acc[0] * INV_COUNT));
}

extern "C" void kernel_launch(void* const* d_in, const int* in_sizes, int n_in,
                              void* d_out, int out_size, void* d_ws, size_t ws_size,
                              hipStream_t stream)
{
    const float* in = (const float*)d_in[0];   // 'input'
    const float* tg = (const float*)d_in[1];   // 'target'
    const float* fl = (const float*)d_in[2];   // 'flow'
    float* out = (float*)d_out;
    double* acc = (double*)d_ws;

    hipMemsetAsync(d_ws, 0, sizeof(double), stream);  // graph-safe memset node

    dim3 grid(NW / TW, NH / TH, NB * NDCH);  // (10, 10, 20) = 2000 blocks
    cc3d_main<<<grid, dim3(256), 0, stream>>>(in, tg, fl, acc);
    cc3d_finalize<<<1, 1, 0, stream>>>(acc, out);
}